// Round 6
// baseline (309.575 us; speedup 1.0000x reference)
//
#include <hip/hip_runtime.h>
#include <hip/hip_fp16.h>
#include <math.h>

#define N_NODES 50000
#define E_EDGES 1600000
#define IN_DIM 128
#define HEADS 4
#define OUT_DIM 32
#define HF 128            // HEADS*OUT_DIM
#define NEG_SLOPE 0.2f
#define CAP 72            // ELL capacity per dst; deg~Poisson(32), P(>72) ~ 1e-8/node

// ---------------------------------------------------------------------------
// Projection: Wh = x @ W  (N x 128 @ 128 x 128) + fused attention halves.
// Wh stored fp16. Block 256, 64 rows/block, 4x8 thread tile.
// ---------------------------------------------------------------------------
__global__ __launch_bounds__(256) void gat_proj(
        const float* __restrict__ x, const float* __restrict__ W,
        const float* __restrict__ att, __half* __restrict__ Whh,
        float* __restrict__ a_src, float* __restrict__ a_dst) {
    __shared__ float Ws[IN_DIM][HF];        // 64 KB
    __shared__ float xs[64][132];           // pad 132: float4-aligned rows
    __shared__ float atts[HEADS][2 * OUT_DIM];

    const int tid = threadIdx.x;

    const float4* W4 = (const float4*)W;
    float4* Ws4 = (float4*)&Ws[0][0];
#pragma unroll
    for (int i = 0; i < 16; ++i) Ws4[tid + 256 * i] = W4[tid + 256 * i];
    if (tid < 64) ((float4*)&atts[0][0])[tid] = ((const float4*)att)[tid];

    const int rowBase = blockIdx.x * 64;
    const int rowsHere = min(64, N_NODES - rowBase);
    const float4* x4 = (const float4*)(x + (size_t)rowBase * IN_DIM);
    for (int i = tid; i < rowsHere * 32; i += 256) {
        const int r = i >> 5, q = i & 31;
        *(float4*)&xs[r][q * 4] = x4[i];
    }
    __syncthreads();

    const int rg = tid >> 4;
    const int cg = tid & 15;
    const int r0 = rg * 4;
    const int c0 = cg * 8;
    const int h  = cg >> 2;
    const int f0 = (cg & 3) * 8;

    float acc[4][8];
#pragma unroll
    for (int i = 0; i < 4; ++i)
#pragma unroll
        for (int j = 0; j < 8; ++j) acc[i][j] = 0.f;

    for (int k0 = 0; k0 < IN_DIM; k0 += 4) {
        float4 a4[4];
#pragma unroll
        for (int i = 0; i < 4; ++i) a4[i] = *(const float4*)&xs[r0 + i][k0];
#pragma unroll
        for (int kk = 0; kk < 4; ++kk) {
            float4 w0 = *(const float4*)&Ws[k0 + kk][c0];
            float4 w1 = *(const float4*)&Ws[k0 + kk][c0 + 4];
            const float wv[8] = {w0.x, w0.y, w0.z, w0.w, w1.x, w1.y, w1.z, w1.w};
            const float av[4] = {(&a4[0].x)[kk], (&a4[1].x)[kk],
                                 (&a4[2].x)[kk], (&a4[3].x)[kk]};
#pragma unroll
            for (int j = 0; j < 8; ++j) {
                acc[0][j] = fmaf(av[0], wv[j], acc[0][j]);
                acc[1][j] = fmaf(av[1], wv[j], acc[1][j]);
                acc[2][j] = fmaf(av[2], wv[j], acc[2][j]);
                acc[3][j] = fmaf(av[3], wv[j], acc[3][j]);
            }
        }
    }

#pragma unroll
    for (int i = 0; i < 4; ++i) {
        const int r = r0 + i;
        if (r >= rowsHere) break;
        const int row = rowBase + r;
        union { __half2 h[4]; float4 f; } u;
        u.h[0] = __floats2half2_rn(acc[i][0], acc[i][1]);
        u.h[1] = __floats2half2_rn(acc[i][2], acc[i][3]);
        u.h[2] = __floats2half2_rn(acc[i][4], acc[i][5]);
        u.h[3] = __floats2half2_rn(acc[i][6], acc[i][7]);
        *(float4*)(Whh + (size_t)row * HF + c0) = u.f;

        float ps = 0.f, pd = 0.f;
#pragma unroll
        for (int j = 0; j < 8; ++j) {
            ps = fmaf(acc[i][j], atts[h][f0 + j], ps);
            pd = fmaf(acc[i][j], atts[h][OUT_DIM + f0 + j], pd);
        }
        ps += __shfl_xor(ps, 1, 64); ps += __shfl_xor(ps, 2, 64);
        pd += __shfl_xor(pd, 1, 64); pd += __shfl_xor(pd, 2, 64);
        if ((cg & 3) == 0) {
            a_src[row * HEADS + h] = ps;
            a_dst[row * HEADS + h] = pd;
        }
    }
}

// ---------------------------------------------------------------------------
// Fused ELL build: slot = atomicAdd(count[dst]); ell[dst*CAP+slot] = src.
// 8 edges/thread -> 8 atomic-returns in flight per lane. No scan, no 2nd pass.
// ---------------------------------------------------------------------------
__global__ __launch_bounds__(256) void gat_ell(
        const int* __restrict__ ei, int* __restrict__ counts,
        int* __restrict__ ell, int cpad) {
    const int t = blockIdx.x * 256 + threadIdx.x;
    if (t >= E_EDGES / 8) return;
    const int4 s4a = ((const int4*)ei)[2 * t];
    const int4 s4b = ((const int4*)ei)[2 * t + 1];
    const int4 d4a = ((const int4*)(ei + E_EDGES))[2 * t];
    const int4 d4b = ((const int4*)(ei + E_EDGES))[2 * t + 1];
    const int s[8] = {s4a.x, s4a.y, s4a.z, s4a.w, s4b.x, s4b.y, s4b.z, s4b.w};
    const int d[8] = {d4a.x, d4a.y, d4a.z, d4a.w, d4b.x, d4b.y, d4b.z, d4b.w};
    int r[8];
#pragma unroll
    for (int i = 0; i < 8; ++i) r[i] = atomicAdd(&counts[d[i] * cpad], 1);
#pragma unroll
    for (int i = 0; i < 8; ++i)
        if (r[i] < CAP) ell[d[i] * CAP + r[i]] = s[i];
}

// ---------------------------------------------------------------------------
// Gather: one 64-lane wave per dst node, half2 per lane = 128 channels.
// Indices batch-loaded from ELL rows and broadcast via shfl; x4 unroll.
// ---------------------------------------------------------------------------
__global__ __launch_bounds__(256) void gat_gather(
        const int* __restrict__ counts, const int* __restrict__ ell,
        const float* __restrict__ a_src, const float* __restrict__ a_dst,
        const __half* __restrict__ Whh, const float* __restrict__ bias,
        float* __restrict__ out, int cpad) {
    const int node = blockIdx.x * 4 + (threadIdx.x >> 6);
    const int lane = threadIdx.x & 63;
    if (node >= N_NODES) return;
    const int h = lane >> 4;
    const float ad = a_dst[node * HEADS + h];
    const __half2* __restrict__ Wh2 = (const __half2*)Whh;

    float accx = 0.f, accy = 0.f, den = 0.f;
    const int cnt = min(counts[node * cpad], CAP);
    const int beg = node * CAP;

    for (int base = 0; base < cnt; base += 64) {
        const int rem = min(64, cnt - base);
        const int idx = (base + lane < cnt) ? ell[beg + base + lane] : 0;
        int j = 0;
        for (; j + 4 <= rem; j += 4) {
            const int s0 = __shfl(idx, j,     64);
            const int s1 = __shfl(idx, j + 1, 64);
            const int s2 = __shfl(idx, j + 2, 64);
            const int s3 = __shfl(idx, j + 3, 64);
            const float as0 = a_src[s0 * 4 + h];
            const float as1 = a_src[s1 * 4 + h];
            const float as2 = a_src[s2 * 4 + h];
            const float as3 = a_src[s3 * 4 + h];
            const __half2 v0 = Wh2[(size_t)s0 * 64 + lane];
            const __half2 v1 = Wh2[(size_t)s1 * 64 + lane];
            const __half2 v2 = Wh2[(size_t)s2 * 64 + lane];
            const __half2 v3 = Wh2[(size_t)s3 * 64 + lane];
            float t0 = as0 + ad; t0 = fmaxf(t0, NEG_SLOPE * t0);
            float t1 = as1 + ad; t1 = fmaxf(t1, NEG_SLOPE * t1);
            float t2 = as2 + ad; t2 = fmaxf(t2, NEG_SLOPE * t2);
            float t3 = as3 + ad; t3 = fmaxf(t3, NEG_SLOPE * t3);
            const float w0 = __expf(t0), w1 = __expf(t1);
            const float w2 = __expf(t2), w3 = __expf(t3);
            const float2 f0 = __half22float2(v0);
            const float2 f1 = __half22float2(v1);
            const float2 f2 = __half22float2(v2);
            const float2 f3 = __half22float2(v3);
            accx = fmaf(w0, f0.x, accx); accy = fmaf(w0, f0.y, accy);
            accx = fmaf(w1, f1.x, accx); accy = fmaf(w1, f1.y, accy);
            accx = fmaf(w2, f2.x, accx); accy = fmaf(w2, f2.y, accy);
            accx = fmaf(w3, f3.x, accx); accy = fmaf(w3, f3.y, accy);
            den += w0 + w1 + w2 + w3;
        }
        for (; j < rem; ++j) {
            const int s = __shfl(idx, j, 64);
            float t = a_src[s * 4 + h] + ad;
            t = fmaxf(t, NEG_SLOPE * t);
            const float w = __expf(t);
            const float2 v = __half22float2(Wh2[(size_t)s * 64 + lane]);
            accx = fmaf(w, v.x, accx);
            accy = fmaf(w, v.y, accy);
            den += w;
        }
    }
    const float inv = 1.f / fmaxf(den, 1e-9f);
    const float2 b2 = ((const float2*)bias)[lane];
    float2 o = {accx * inv + b2.x, accy * inv + b2.y};
    ((float2*)out)[(size_t)node * 64 + lane] = o;
}

// ---------------------------------------------------------------------------
extern "C" void kernel_launch(void* const* d_in, const int* in_sizes, int n_in,
                              void* d_out, int out_size, void* d_ws, size_t ws_size,
                              hipStream_t stream) {
    const float* x    = (const float*)d_in[0];
    const int*   ei   = (const int*)d_in[1];   // [2, E]
    const float* W    = (const float*)d_in[2];
    const float* att  = (const float*)d_in[3];
    const float* bias = (const float*)d_in[4];
    float* out = (float*)d_out;

    // Workspace: Whh[N*128 half] | a_src[N*4] | a_dst[N*4] | ell[N*CAP]
    //            | counts[N*cpad]   (cpad chosen to fit ws_size)
    __half* Whh   = (__half*)d_ws;
    float* a_src  = (float*)(Whh + (size_t)N_NODES * HF);
    float* a_dst  = a_src + (size_t)N_NODES * HEADS;
    int*   ell    = (int*)(a_dst + (size_t)N_NODES * HEADS);
    int*   counts = ell + (size_t)N_NODES * CAP;

    const size_t base_bytes = (size_t)N_NODES * HF * 2 +          // Whh
                              (size_t)N_NODES * HEADS * 4 * 2 +   // a_src/a_dst
                              (size_t)N_NODES * CAP * 4;          // ell
    int cpad = 4;
    if (ws_size >= base_bytes + (size_t)N_NODES * 16 * 4)      cpad = 16;
    else if (ws_size >= base_bytes + (size_t)N_NODES * 8 * 4)  cpad = 8;

    hipMemsetAsync(counts, 0, (size_t)N_NODES * cpad * 4, stream);
    gat_proj<<<(N_NODES + 63) / 64, 256, 0, stream>>>(x, W, att, Whh, a_src, a_dst);
    gat_ell<<<(E_EDGES / 8 + 255) / 256, 256, 0, stream>>>(ei, counts, ell, cpad);
    gat_gather<<<(N_NODES + 3) / 4, 256, 0, stream>>>(counts, ell, a_src, a_dst,
                                                      Whh, bias, out, cpad);
}